// Round 1
// 240.598 us; speedup vs baseline: 1.0257x; 1.0257x over previous
//
#include <hip/hip_runtime.h>

#define D_CH   1024
#define L_SEQ  8192
#define W_N    3.8349519697141029e-4f   /* 2*pi/16384 */
#define W128A  4.90873852123405e-2f     /* 2*pi/128 */

// ---------------- bf16 pack/unpack --------------------------------------
__device__ __forceinline__ float bf2f(unsigned v){
  union { float f; unsigned u; } x; x.u = v << 16;
  return x.f;
}
// single-instruction RNE pack of (r,i) -> bf16|bf16<<16 (no builtin on gfx950)
__device__ __forceinline__ unsigned packc(float r, float i){
  unsigned u;
  asm("v_cvt_pk_bf16_f32 %0, %1, %2" : "=v"(u) : "v"(r), "v"(i));
  return u;
}
__device__ __forceinline__ float2 upk(unsigned u){
  return make_float2(bf2f(u & 0xffffu), bf2f(u >> 16));
}

__device__ __host__ constexpr int bitrev4(int j){
  return ((j&1)<<3)|((j&2)<<1)|((j&4)>>1)|((j&8)>>3);
}
__device__ __host__ constexpr int bitrev3(int j){
  return ((j&1)<<2)|(j&2)|((j&4)>>2);
}

// 16-pt DIF DFT, natural in; slot j holds X[bitrev4(j)].
template<int SGN>
__device__ __forceinline__ void dft16(float2* x){
  const float TC[8] = {1.f, 0.9238795325f, 0.7071067812f, 0.3826834324f,
                       0.f, -0.3826834324f, -0.7071067812f, -0.9238795325f};
  const float TS[8] = {0.f, -0.3826834324f, -0.7071067812f, -0.9238795325f,
                       -1.f, -0.9238795325f, -0.7071067812f, -0.3826834324f};
#pragma unroll
  for (int len = 16; len >= 2; len >>= 1){
    const int half = len >> 1, tstep = 16 / len;
#pragma unroll
    for (int st = 0; st < 16; st += len){
#pragma unroll
      for (int j = 0; j < half; j++){
        const float wr = TC[j*tstep];
        const float wi = (SGN > 0) ? TS[j*tstep] : -TS[j*tstep];
        const int a = st + j, b = a + half;
        const float ur = x[a].x, ui = x[a].y;
        const float vr = x[b].x, vi = x[b].y;
        x[a].x = ur + vr; x[a].y = ui + vi;
        const float dr = ur - vr, di = ui - vi;
        x[b].x = dr*wr - di*wi;
        x[b].y = dr*wi + di*wr;
      }
    }
  }
}

// 8-pt DIF DFT, natural in; slot j holds X[bitrev3(j)].
template<int SGN>
__device__ __forceinline__ void dft8(float2* x){
  const float TC[4] = {1.f, 0.7071067812f, 0.f, -0.7071067812f};
  const float TS[4] = {0.f, -0.7071067812f, -1.f, -0.7071067812f};
#pragma unroll
  for (int len = 8; len >= 2; len >>= 1){
    const int half = len >> 1, tstep = 8 / len;
#pragma unroll
    for (int st = 0; st < 8; st += len){
#pragma unroll
      for (int j = 0; j < half; j++){
        const float wr = TC[j*tstep];
        const float wi = (SGN > 0) ? TS[j*tstep] : -TS[j*tstep];
        const int a = st + j, b = a + half;
        const float ur = x[a].x, ui = x[a].y;
        const float vr = x[b].x, vi = x[b].y;
        x[a].x = ur + vr; x[a].y = ui + vi;
        const float dr = ur - vr, di = ui - vi;
        x[b].x = dr*wr - di*wi;
        x[b].y = dr*wi + di*wr;
      }
    }
  }
}

// Per-block twiddle table for fft128: twF[p*16+k] = e^{-i*2pi*p*k/128}.
// Wave-uniform broadcast reads at use; inverse transform conjugates at use.
__device__ __forceinline__ void build_twF(float2* twF, int tid){
  if (tid < 128){
    const int pp = tid >> 4, kk = tid & 15;
    float sn, cs;
    __sincosf(-W128A * (float)(pp * kk), &sn, &cs);
    twF[tid] = make_float2(cs, sn);
  }
}

// 128-pt DFT across 8 p-threads (p = tid>>6) x 64 channels (lane).
// Entry: v[q] = f[p + 8q]. Exit: v[c*8+t] = F[(2p+c) + 16*bitrev3(t)].
// Twiddles come from the LDS table twF (caller must barrier after build).
// 3 internal barriers. Caller must __syncthreads() before reusing lds.
template<int SGN>
__device__ __forceinline__ void fft128(float2* v, float2* lds,
                                       const float2* twF, int lane, int p){
  dft16<SGN>(v);                         // slot -> s = bitrev4(slot)
  // ---- phase 0: slots 0..7 (s = 2r even, r = bitrev3(slot)) ----
#pragma unroll
  for (int slot = 0; slot < 8; slot++){
    const int r = bitrev3(slot);
    const float2 t = twF[p*16 + 2*r];
    const float cs = t.x;
    const float sn = (SGN > 0) ? t.y : -t.y;
    const float2 a = v[slot];
    lds[(p*8 + r)*64 + lane] = make_float2(a.x*cs - a.y*sn, a.x*sn + a.y*cs);
  }
  __syncthreads();
  float2 t8[8];
#pragma unroll
  for (int pp = 0; pp < 8; pp++) t8[pp] = lds[(pp*8 + p)*64 + lane]; // s=2p
  dft8<SGN>(t8);
#pragma unroll
  for (int t = 0; t < 8; t++) v[t] = t8[t];
  __syncthreads();                       // reads done before phase-1 stores
  // ---- phase 1: slots 8..15 (s = 2r+1 odd) ----
#pragma unroll
  for (int slot = 8; slot < 16; slot++){
    const int r = bitrev3(slot - 8);
    const float2 t = twF[p*16 + 2*r + 1];
    const float cs = t.x;
    const float sn = (SGN > 0) ? t.y : -t.y;
    const float2 a = v[slot];
    lds[(p*8 + r)*64 + lane] = make_float2(a.x*cs - a.y*sn, a.x*sn + a.y*cs);
  }
  __syncthreads();
#pragma unroll
  for (int pp = 0; pp < 8; pp++) t8[pp] = lds[(pp*8 + p)*64 + lane]; // s=2p+1
  dft8<SGN>(t8);
#pragma unroll
  for (int t = 0; t < 8; t++) v[8 + t] = t8[t];
}

// ---------------------------------------------------------------------------
// K1: forward step1 over n1 (64 nonzero of 128, zero-padded).
// A[k1,n2] = w16384^{k1 n2} * DFT128_{n1}(z[n2+128 n1]).
// mode 0: z = x[0] + i x[1]; mode 1: h.
// ---------------------------------------------------------------------------
__global__ __launch_bounds__(512, 8)
void k1_step1(const float* __restrict__ x, const float* __restrict__ h,
              unsigned* __restrict__ Az, unsigned* __restrict__ Ah){
  __shared__ float2 lds[4096];
  __shared__ float2 twF[128];
  __shared__ float2 twO[128];
  const int n2 = blockIdx.x, dg = blockIdx.y, mode = blockIdx.z;
  const int tid = threadIdx.x;
  const int lane = tid & 63, p = tid >> 6;
  const int d = dg*64 + lane;

  // per-block twiddle tables: each thread does at most ONE sincos
  build_twF(twF, tid);
  if (tid >= 128 && tid < 256){
    const int k1v = tid - 128;
    float sn, cs;
    __sincosf(-W_N * (float)(k1v * n2), &sn, &cs);   // e^{-i 2pi k1 n2 /16384}
    twO[k1v] = make_float2(cs, sn);
  }

  float2 v[16];
  if (mode == 0){
    const float* x0 = x;
    const float* x1 = x + (size_t)L_SEQ * D_CH;
#pragma unroll
    for (int q = 0; q < 8; q++){
      const size_t off = (size_t)(n2 + 128*(p + 8*q)) * D_CH + d;
      v[q] = make_float2(x0[off], x1[off]);
    }
  } else {
#pragma unroll
    for (int q = 0; q < 8; q++){
      const size_t off = (size_t)(n2 + 128*(p + 8*q)) * D_CH + d;
      v[q] = make_float2(h[off], 0.0f);
    }
  }
#pragma unroll
  for (int q = 8; q < 16; q++) v[q] = make_float2(0.f, 0.f);

  __syncthreads();                       // twiddle tables visible
  fft128<1>(v, lds, twF, lane, p);

  unsigned* __restrict__ A = mode ? Ah : Az;
#pragma unroll
  for (int c = 0; c < 2; c++){
#pragma unroll
    for (int t = 0; t < 8; t++){
      const int k1v = (2*p + c) + 16*bitrev3(t);
      const float2 w = twO[k1v];         // broadcast read, written pre-barrier
      const float2 a = v[c*8 + t];
      A[((size_t)k1v*128 + n2)*D_CH + d] =
        packc(a.x*w.x - a.y*w.y, a.x*w.y + a.y*w.x);
    }
  }
}

// ---------------------------------------------------------------------------
// K2 (fused): forward step2 for h (in-register Hspec, never stored) +
// forward step2 for z + pointwise Z*H/16384 + inverse DFT over k2,
// in place on A_z: result b[k1,m2] stored at natural m2.
// ---------------------------------------------------------------------------
__global__ __launch_bounds__(512, 4)
void k2_zh(unsigned* __restrict__ Az, const unsigned* __restrict__ Ah){
  __shared__ float2 lds[4096];
  __shared__ float2 twF[128];
  const int k1 = blockIdx.x, dg = blockIdx.y;
  const int tid = threadIdx.x;
  const int lane = tid & 63, p = tid >> 6;
  const int d = dg*64 + lane;
  const size_t base = (size_t)k1 * 128 * D_CH + d;

  build_twF(twF, tid);

  // issue all independent loads up front (MLP)
  unsigned ha[16], za[16];
#pragma unroll
  for (int q = 0; q < 16; q++)
    ha[q] = Ah[base + (size_t)(p + 8*q) * D_CH];
#pragma unroll
  for (int q = 0; q < 16; q++)
    za[q] = Az[base + (size_t)(p + 8*q) * D_CH];

  __syncthreads();                       // twF visible

  // ---- H: forward 128-pt over n2, keep spectrum packed in regs ----
  float2 v[16];
#pragma unroll
  for (int q = 0; q < 16; q++) v[q] = upk(ha[q]);
  fft128<1>(v, lds, twF, lane, p);
  unsigned hs[16];
  const float sc = 1.0f / 16384.0f;      // fold ifft scale into Hspec
#pragma unroll
  for (int i = 0; i < 16; i++) hs[i] = packc(v[i].x * sc, v[i].y * sc);
  __syncthreads();                       // lds reads done before z-fft stores

  // ---- Z: forward 128-pt over n2 ----
#pragma unroll
  for (int q = 0; q < 16; q++) v[q] = upk(za[q]);
  fft128<1>(v, lds, twF, lane, p);

  // ---- pointwise multiply (orders match) ----
#pragma unroll
  for (int i = 0; i < 16; i++){
    const float2 hv = upk(hs[i]);
    const float zr = v[i].x, zi = v[i].y;
    v[i] = make_float2(zr*hv.x - zi*hv.y, zr*hv.y + zi*hv.x);
  }

  // ---- redistribute to natural k2 order: v[q] = Y[p+8q] ----
  __syncthreads();                       // protect fft128's lds reads
  float2 w[16];
  // phase A: k2 < 64  (t even)
#pragma unroll
  for (int c = 0; c < 2; c++)
#pragma unroll
    for (int t = 0; t < 8; t += 2){
      const int k2 = (2*p + c) + 16*bitrev3(t);
      lds[k2*64 + lane] = v[c*8 + t];
    }
  __syncthreads();
#pragma unroll
  for (int q = 0; q < 8; q++) w[q] = lds[(p + 8*q)*64 + lane];
  __syncthreads();
  // phase B: k2 >= 64 (t odd)
#pragma unroll
  for (int c = 0; c < 2; c++)
#pragma unroll
    for (int t = 1; t < 8; t += 2){
      const int k2 = (2*p + c) + 16*bitrev3(t) - 64;
      lds[k2*64 + lane] = v[c*8 + t];
    }
  __syncthreads();
#pragma unroll
  for (int q = 0; q < 8; q++) w[8 + q] = lds[(p + 8*q)*64 + lane];
  __syncthreads();                       // reads done before inverse stores
#pragma unroll
  for (int q = 0; q < 16; q++) v[q] = w[q];

  // ---- inverse 128-pt over k2 ----
  fft128<-1>(v, lds, twF, lane, p);      // v[c*8+t] = b at m2=(2p+c)+16*bitrev3(t)

#pragma unroll
  for (int c = 0; c < 2; c++){
#pragma unroll
    for (int t = 0; t < 8; t++){
      const int m2 = (2*p + c) + 16*bitrev3(t);
      const float2 a = v[c*8 + t];
      Az[base + (size_t)m2 * D_CH] = packc(a.x, a.y);
    }
  }
}

// ---------------------------------------------------------------------------
// K3: inverse step2 over k1 + bias + output write.
// y[0,t,d] = Re(w)+bias, y[1,t,d] = Im(w)+bias, t = m2 + 128*m1, m1 < 64.
// ---------------------------------------------------------------------------
__global__ __launch_bounds__(512, 6)
void k3_inv2(const unsigned* __restrict__ Bz, const float* __restrict__ bias,
             float* __restrict__ out){
  __shared__ float2 lds[4096];
  __shared__ float2 twF[128];
  __shared__ float2 twI[128];
  const int m2 = blockIdx.x, dg = blockIdx.y;
  const int tid = threadIdx.x;
  const int lane = tid & 63, p = tid >> 6;
  const int d = dg*64 + lane;
  const float bv = bias[d];

  build_twF(twF, tid);
  if (tid >= 128 && tid < 256){
    const int k1 = tid - 128;
    float sn, cs;
    __sincosf(W_N * (float)(m2 * k1), &sn, &cs);     // e^{+i 2pi m2 k1 /16384}
    twI[k1] = make_float2(cs, sn);
  }

  unsigned raw[16];
#pragma unroll
  for (int q = 0; q < 16; q++){
    const int k1 = p + 8*q;
    raw[q] = Bz[((size_t)k1*128 + m2) * D_CH + d];
  }

  __syncthreads();                       // tables visible

  float2 v[16];
#pragma unroll
  for (int q = 0; q < 16; q++){
    const float2 w = twI[p + 8*q];       // broadcast read
    const float2 a = upk(raw[q]);
    v[q] = make_float2(a.x*w.x - a.y*w.y, a.x*w.y + a.y*w.x);
  }

  fft128<-1>(v, lds, twF, lane, p);      // v[c*8+t] = w[m1=(2p+c)+16*bitrev3(t)]

#pragma unroll
  for (int c = 0; c < 2; c++){
#pragma unroll
    for (int t = 0; t < 8; t += 2){      // t even <=> bitrev3(t)<4 <=> m1 < 64
      const int m1 = (2*p + c) + 16*bitrev3(t);
      const int tseq = m2 + 128*m1;
      const float2 a = v[c*8 + t];
      out[(size_t)tseq * D_CH + d]            = a.x + bv;
      out[(size_t)(L_SEQ + tseq) * D_CH + d]  = a.y + bv;
    }
  }
}

// ---------------------------------------------------------------------------
extern "C" void kernel_launch(void* const* d_in, const int* in_sizes, int n_in,
                              void* d_out, int out_size, void* d_ws, size_t ws_size,
                              hipStream_t stream){
  (void)in_sizes; (void)n_in; (void)out_size;
  const float* x    = (const float*)d_in[0];
  const float* h    = (const float*)d_in[1];
  const float* bias = (const float*)d_in[2];
  float* out = (float*)d_out;

  const size_t REGION = (size_t)128 * 128 * D_CH * sizeof(unsigned); // 64 MiB
  unsigned *r1, *r2;
  if (ws_size >= 2 * REGION){
    r1 = (unsigned*)d_ws;                       // A_z -> b
    r2 = (unsigned*)((char*)d_ws + REGION);     // A_h
  } else {
    r1 = (unsigned*)d_out;  // safe: K3 reads each r1 cell before its stores
    r2 = (unsigned*)d_ws;   // requires ws_size >= 64 MiB
  }

  const dim3 blk(512, 1, 1);
  hipLaunchKernelGGL(k1_step1, dim3(128,16,2), blk, 0, stream, x, h, r1, r2);
  hipLaunchKernelGGL(k2_zh,    dim3(128,16,1), blk, 0, stream, r1, r2);
  hipLaunchKernelGGL(k3_inv2,  dim3(128,16,1), blk, 0, stream, r1, bias, out);
}

// Round 2
// 235.266 us; speedup vs baseline: 1.0489x; 1.0227x over previous
//
#include <hip/hip_runtime.h>

#define D_CH   1024
#define L_SEQ  8192
#define NCH    32                       /* channels per block */
#define W_N    3.8349519697141029e-4f   /* 2*pi/16384 */
#define W128A  4.90873852123405e-2f     /* 2*pi/128 */

// ---------------- bf16 pack/unpack --------------------------------------
__device__ __forceinline__ float bf2f(unsigned v){
  union { float f; unsigned u; } x; x.u = v << 16;
  return x.f;
}
// single-instruction RNE pack of (r,i) -> bf16|bf16<<16 (no builtin on gfx950)
__device__ __forceinline__ unsigned packc(float r, float i){
  unsigned u;
  asm("v_cvt_pk_bf16_f32 %0, %1, %2" : "=v"(u) : "v"(r), "v"(i));
  return u;
}
__device__ __forceinline__ float2 upk(unsigned u){
  return make_float2(bf2f(u & 0xffffu), bf2f(u >> 16));
}

__device__ __host__ constexpr int bitrev4(int j){
  return ((j&1)<<3)|((j&2)<<1)|((j&4)>>1)|((j&8)>>3);
}
__device__ __host__ constexpr int bitrev3(int j){
  return ((j&1)<<2)|(j&2)|((j&4)>>2);
}

// 16-pt DIF DFT, natural in; slot j holds X[bitrev4(j)].
template<int SGN>
__device__ __forceinline__ void dft16(float2* x){
  const float TC[8] = {1.f, 0.9238795325f, 0.7071067812f, 0.3826834324f,
                       0.f, -0.3826834324f, -0.7071067812f, -0.9238795325f};
  const float TS[8] = {0.f, -0.3826834324f, -0.7071067812f, -0.9238795325f,
                       -1.f, -0.9238795325f, -0.7071067812f, -0.3826834324f};
#pragma unroll
  for (int len = 16; len >= 2; len >>= 1){
    const int half = len >> 1, tstep = 16 / len;
#pragma unroll
    for (int st = 0; st < 16; st += len){
#pragma unroll
      for (int j = 0; j < half; j++){
        const float wr = TC[j*tstep];
        const float wi = (SGN > 0) ? TS[j*tstep] : -TS[j*tstep];
        const int a = st + j, b = a + half;
        const float ur = x[a].x, ui = x[a].y;
        const float vr = x[b].x, vi = x[b].y;
        x[a].x = ur + vr; x[a].y = ui + vi;
        const float dr = ur - vr, di = ui - vi;
        x[b].x = dr*wr - di*wi;
        x[b].y = dr*wi + di*wr;
      }
    }
  }
}

// 8-pt DIF DFT, natural in; slot j holds X[bitrev3(j)].
template<int SGN>
__device__ __forceinline__ void dft8(float2* x){
  const float TC[4] = {1.f, 0.7071067812f, 0.f, -0.7071067812f};
  const float TS[4] = {0.f, -0.7071067812f, -1.f, -0.7071067812f};
#pragma unroll
  for (int len = 8; len >= 2; len >>= 1){
    const int half = len >> 1, tstep = 8 / len;
#pragma unroll
    for (int st = 0; st < 8; st += len){
#pragma unroll
      for (int j = 0; j < half; j++){
        const float wr = TC[j*tstep];
        const float wi = (SGN > 0) ? TS[j*tstep] : -TS[j*tstep];
        const int a = st + j, b = a + half;
        const float ur = x[a].x, ui = x[a].y;
        const float vr = x[b].x, vi = x[b].y;
        x[a].x = ur + vr; x[a].y = ui + vi;
        const float dr = ur - vr, di = ui - vi;
        x[b].x = dr*wr - di*wi;
        x[b].y = dr*wi + di*wr;
      }
    }
  }
}

// Per-block twiddle table for fft128: twF[p*16+k] = e^{-i*2pi*p*k/128}.
__device__ __forceinline__ void build_twF(float2* twF, int tid){
  if (tid < 128){
    const int pp = tid >> 4, kk = tid & 15;
    float sn, cs;
    __sincosf(-W128A * (float)(pp * kk), &sn, &cs);
    twF[tid] = make_float2(cs, sn);
  }
}

// 128-pt DFT across 8 p-threads (p = tid>>5) x NCH channels (ch = tid&31).
// Entry: v[q] = f[p + 8q]. Exit: v[c*8+t] = F[(2p+c) + 16*bitrev3(t)].
// LDS buffer: float2[64*NCH] = 16 KiB. 3 internal barriers; caller must
// __syncthreads() before reusing lds afterwards.
template<int SGN>
__device__ __forceinline__ void fft128(float2* v, float2* lds,
                                       const float2* twF, int ch, int p){
  dft16<SGN>(v);                         // slot -> s = bitrev4(slot)
  // ---- phase 0: slots 0..7 (s = 2r even, r = bitrev3(slot)) ----
#pragma unroll
  for (int slot = 0; slot < 8; slot++){
    const int r = bitrev3(slot);
    const float2 t = twF[p*16 + 2*r];
    const float cs = t.x;
    const float sn = (SGN > 0) ? t.y : -t.y;
    const float2 a = v[slot];
    lds[(p*8 + r)*NCH + ch] = make_float2(a.x*cs - a.y*sn, a.x*sn + a.y*cs);
  }
  __syncthreads();
  float2 t8[8];
#pragma unroll
  for (int pp = 0; pp < 8; pp++) t8[pp] = lds[(pp*8 + p)*NCH + ch]; // s=2p
  dft8<SGN>(t8);
#pragma unroll
  for (int t = 0; t < 8; t++) v[t] = t8[t];
  __syncthreads();                       // reads done before phase-1 stores
  // ---- phase 1: slots 8..15 (s = 2r+1 odd) ----
#pragma unroll
  for (int slot = 8; slot < 16; slot++){
    const int r = bitrev3(slot - 8);
    const float2 t = twF[p*16 + 2*r + 1];
    const float cs = t.x;
    const float sn = (SGN > 0) ? t.y : -t.y;
    const float2 a = v[slot];
    lds[(p*8 + r)*NCH + ch] = make_float2(a.x*cs - a.y*sn, a.x*sn + a.y*cs);
  }
  __syncthreads();
#pragma unroll
  for (int pp = 0; pp < 8; pp++) t8[pp] = lds[(pp*8 + p)*NCH + ch]; // s=2p+1
  dft8<SGN>(t8);
#pragma unroll
  for (int t = 0; t < 8; t++) v[8 + t] = t8[t];
}

// ---------------------------------------------------------------------------
// K1: forward step1 over n1 (64 nonzero of 128, zero-padded).
// A[k1,n2] = w16384^{k1 n2} * DFT128_{n1}(z[n2+128 n1]).
// mode 0: z = x[0] + i x[1]; mode 1: h.
// ---------------------------------------------------------------------------
__global__ __launch_bounds__(256, 8)
void k1_step1(const float* __restrict__ x, const float* __restrict__ h,
              unsigned* __restrict__ Az, unsigned* __restrict__ Ah){
  __shared__ float2 lds[64*NCH];
  __shared__ float2 twF[128];
  __shared__ float2 twO[128];
  const int n2 = blockIdx.x, dg = blockIdx.y, mode = blockIdx.z;
  const int tid = threadIdx.x;
  const int ch = tid & (NCH-1), p = tid >> 5;
  const int d = dg*NCH + ch;

  // per-block twiddle tables: each thread does at most ONE sincos
  build_twF(twF, tid);
  if (tid >= 128 && tid < 256){
    const int k1v = tid - 128;
    float sn, cs;
    __sincosf(-W_N * (float)(k1v * n2), &sn, &cs);   // e^{-i 2pi k1 n2 /16384}
    twO[k1v] = make_float2(cs, sn);
  }

  float2 v[16];
  if (mode == 0){
    const float* x0 = x;
    const float* x1 = x + (size_t)L_SEQ * D_CH;
#pragma unroll
    for (int q = 0; q < 8; q++){
      const size_t off = (size_t)(n2 + 128*(p + 8*q)) * D_CH + d;
      v[q] = make_float2(x0[off], x1[off]);
    }
  } else {
#pragma unroll
    for (int q = 0; q < 8; q++){
      const size_t off = (size_t)(n2 + 128*(p + 8*q)) * D_CH + d;
      v[q] = make_float2(h[off], 0.0f);
    }
  }
#pragma unroll
  for (int q = 8; q < 16; q++) v[q] = make_float2(0.f, 0.f);

  __syncthreads();                       // twiddle tables visible
  fft128<1>(v, lds, twF, ch, p);

  unsigned* __restrict__ A = mode ? Ah : Az;
#pragma unroll
  for (int c = 0; c < 2; c++){
#pragma unroll
    for (int t = 0; t < 8; t++){
      const int k1v = (2*p + c) + 16*bitrev3(t);
      const float2 w = twO[k1v];         // broadcast read, written pre-barrier
      const float2 a = v[c*8 + t];
      A[((size_t)k1v*128 + n2)*D_CH + d] =
        packc(a.x*w.x - a.y*w.y, a.x*w.y + a.y*w.x);
    }
  }
}

// ---------------------------------------------------------------------------
// K2 (fused): forward step2 for h (in-register Hspec, never stored) +
// forward step2 for z + pointwise Z*H/16384 + inverse DFT over k2,
// in place on A_z: result b[k1,m2] stored at natural m2.
// ---------------------------------------------------------------------------
__global__ __launch_bounds__(256, 4)
void k2_zh(unsigned* __restrict__ Az, const unsigned* __restrict__ Ah){
  __shared__ float2 lds[64*NCH];
  __shared__ float2 twF[128];
  const int k1 = blockIdx.x, dg = blockIdx.y;
  const int tid = threadIdx.x;
  const int ch = tid & (NCH-1), p = tid >> 5;
  const int d = dg*NCH + ch;
  const size_t base = (size_t)k1 * 128 * D_CH + d;

  build_twF(twF, tid);

  // issue all independent loads up front (MLP)
  unsigned ha[16], za[16];
#pragma unroll
  for (int q = 0; q < 16; q++)
    ha[q] = Ah[base + (size_t)(p + 8*q) * D_CH];
#pragma unroll
  for (int q = 0; q < 16; q++)
    za[q] = Az[base + (size_t)(p + 8*q) * D_CH];

  __syncthreads();                       // twF visible

  // ---- H: forward 128-pt over n2, keep spectrum packed in regs ----
  float2 v[16];
#pragma unroll
  for (int q = 0; q < 16; q++) v[q] = upk(ha[q]);
  fft128<1>(v, lds, twF, ch, p);
  unsigned hs[16];
  const float sc = 1.0f / 16384.0f;      // fold ifft scale into Hspec
#pragma unroll
  for (int i = 0; i < 16; i++) hs[i] = packc(v[i].x * sc, v[i].y * sc);
  __syncthreads();                       // lds reads done before z-fft stores

  // ---- Z: forward 128-pt over n2 ----
#pragma unroll
  for (int q = 0; q < 16; q++) v[q] = upk(za[q]);
  fft128<1>(v, lds, twF, ch, p);

  // ---- pointwise multiply (orders match) ----
#pragma unroll
  for (int i = 0; i < 16; i++){
    const float2 hv = upk(hs[i]);
    const float zr = v[i].x, zi = v[i].y;
    v[i] = make_float2(zr*hv.x - zi*hv.y, zr*hv.y + zi*hv.x);
  }

  // ---- redistribute to natural k2 order: v[q] = Y[p+8q] ----
  __syncthreads();                       // protect fft128's lds reads
  float2 w[8];
  // phase A: k2 < 64  (t even)
#pragma unroll
  for (int c = 0; c < 2; c++)
#pragma unroll
    for (int t = 0; t < 8; t += 2){
      const int k2 = (2*p + c) + 16*bitrev3(t);
      lds[k2*NCH + ch] = v[c*8 + t];
    }
  __syncthreads();
#pragma unroll
  for (int q = 0; q < 8; q++) w[q] = lds[(p + 8*q)*NCH + ch];
  __syncthreads();
  // phase B: k2 >= 64 (t odd)
#pragma unroll
  for (int c = 0; c < 2; c++)
#pragma unroll
    for (int t = 1; t < 8; t += 2){
      const int k2 = (2*p + c) + 16*bitrev3(t) - 64;
      lds[k2*NCH + ch] = v[c*8 + t];
    }
  __syncthreads();
#pragma unroll
  for (int q = 0; q < 8; q++) v[8 + q] = lds[(p + 8*q)*NCH + ch];
  __syncthreads();                       // reads done before inverse stores
#pragma unroll
  for (int q = 0; q < 8; q++) v[q] = w[q];

  // ---- inverse 128-pt over k2 ----
  fft128<-1>(v, lds, twF, ch, p);        // v[c*8+t] = b at m2=(2p+c)+16*bitrev3(t)

#pragma unroll
  for (int c = 0; c < 2; c++){
#pragma unroll
    for (int t = 0; t < 8; t++){
      const int m2 = (2*p + c) + 16*bitrev3(t);
      const float2 a = v[c*8 + t];
      Az[base + (size_t)m2 * D_CH] = packc(a.x, a.y);
    }
  }
}

// ---------------------------------------------------------------------------
// K3: inverse step2 over k1 + bias + output write.
// y[0,t,d] = Re(w)+bias, y[1,t,d] = Im(w)+bias, t = m2 + 128*m1, m1 < 64.
// ---------------------------------------------------------------------------
__global__ __launch_bounds__(256, 6)
void k3_inv2(const unsigned* __restrict__ Bz, const float* __restrict__ bias,
             float* __restrict__ out){
  __shared__ float2 lds[64*NCH];
  __shared__ float2 twF[128];
  __shared__ float2 twI[128];
  const int m2 = blockIdx.x, dg = blockIdx.y;
  const int tid = threadIdx.x;
  const int ch = tid & (NCH-1), p = tid >> 5;
  const int d = dg*NCH + ch;
  const float bv = bias[d];

  build_twF(twF, tid);
  if (tid >= 128 && tid < 256){
    const int k1 = tid - 128;
    float sn, cs;
    __sincosf(W_N * (float)(m2 * k1), &sn, &cs);     // e^{+i 2pi m2 k1 /16384}
    twI[k1] = make_float2(cs, sn);
  }

  unsigned raw[16];
#pragma unroll
  for (int q = 0; q < 16; q++){
    const int k1 = p + 8*q;
    raw[q] = Bz[((size_t)k1*128 + m2) * D_CH + d];
  }

  __syncthreads();                       // tables visible

  float2 v[16];
#pragma unroll
  for (int q = 0; q < 16; q++){
    const float2 w = twI[p + 8*q];       // broadcast read
    const float2 a = upk(raw[q]);
    v[q] = make_float2(a.x*w.x - a.y*w.y, a.x*w.y + a.y*w.x);
  }

  fft128<-1>(v, lds, twF, ch, p);        // v[c*8+t] = w[m1=(2p+c)+16*bitrev3(t)]

#pragma unroll
  for (int c = 0; c < 2; c++){
#pragma unroll
    for (int t = 0; t < 8; t += 2){      // t even <=> bitrev3(t)<4 <=> m1 < 64
      const int m1 = (2*p + c) + 16*bitrev3(t);
      const int tseq = m2 + 128*m1;
      const float2 a = v[c*8 + t];
      out[(size_t)tseq * D_CH + d]            = a.x + bv;
      out[(size_t)(L_SEQ + tseq) * D_CH + d]  = a.y + bv;
    }
  }
}

// ---------------------------------------------------------------------------
extern "C" void kernel_launch(void* const* d_in, const int* in_sizes, int n_in,
                              void* d_out, int out_size, void* d_ws, size_t ws_size,
                              hipStream_t stream){
  (void)in_sizes; (void)n_in; (void)out_size;
  const float* x    = (const float*)d_in[0];
  const float* h    = (const float*)d_in[1];
  const float* bias = (const float*)d_in[2];
  float* out = (float*)d_out;

  const size_t REGION = (size_t)128 * 128 * D_CH * sizeof(unsigned); // 64 MiB
  unsigned *r1, *r2;
  if (ws_size >= 2 * REGION){
    r1 = (unsigned*)d_ws;                       // A_z -> b
    r2 = (unsigned*)((char*)d_ws + REGION);     // A_h
  } else {
    r1 = (unsigned*)d_out;  // safe: K3 reads each r1 cell before its stores
    r2 = (unsigned*)d_ws;   // requires ws_size >= 64 MiB
  }

  const dim3 blk(256, 1, 1);
  hipLaunchKernelGGL(k1_step1, dim3(128,32,2), blk, 0, stream, x, h, r1, r2);
  hipLaunchKernelGGL(k2_zh,    dim3(128,32,1), blk, 0, stream, r1, r2);
  hipLaunchKernelGGL(k3_inv2,  dim3(128,32,1), blk, 0, stream, r1, bias, out);
}